// Round 1
// baseline (312.120 us; speedup 1.0000x reference)
//
#include <hip/hip_runtime.h>
#include <hip/hip_bf16.h>

typedef unsigned short ushort_t;
typedef unsigned int uint_t;
typedef __attribute__((ext_vector_type(4))) float f32x4;
typedef __attribute__((ext_vector_type(8))) short short8;
typedef __attribute__((ext_vector_type(4))) unsigned short u16x4;

#define S_LEN 2048
#define DM 1024
#define NH 16
#define DH 64
#define NB 2
#define BH (NB*NH)          // 32
#define MROWS (NB*S_LEN)    // 4096

__device__ __forceinline__ float bf2f(ushort_t u) {
    return __uint_as_float(((uint_t)u) << 16);
}
__device__ __forceinline__ ushort_t f2bf(float f) {
    __hip_bfloat16 h = __float2bfloat16(f);
    return *reinterpret_cast<ushort_t*>(&h);
}

// ---------------------------------------------------------------- convert
// X (4096x1024) and 4 weights (1024x1024 each) fp32 -> bf16
__global__ __launch_bounds__(256) void convert_all(
    const float* __restrict__ X,  const float* __restrict__ Wq,
    const float* __restrict__ Wk, const float* __restrict__ Wv,
    const float* __restrict__ Wo,
    ushort_t* __restrict__ Xb,  ushort_t* __restrict__ Wqb,
    ushort_t* __restrict__ Wkb, ushort_t* __restrict__ Wvb,
    ushort_t* __restrict__ Wob)
{
    size_t i = (size_t)blockIdx.x * 256 + threadIdx.x;   // 2,097,152 threads
    size_t e = i * 4;
    const float* src; ushort_t* dst; size_t off;
    if (e < (size_t)MROWS * DM) { src = X; dst = Xb; off = e; }
    else {
        size_t r = e - (size_t)MROWS * DM;
        int w = (int)(r >> 20); off = r & 1048575;
        src = (w == 0) ? Wq : (w == 1) ? Wk : (w == 2) ? Wv : Wo;
        dst = (w == 0) ? Wqb : (w == 1) ? Wkb : (w == 2) ? Wvb : Wob;
    }
    float4 v = *reinterpret_cast<const float4*>(src + off);
    u16x4 o;
    o[0] = f2bf(v.x); o[1] = f2bf(v.y); o[2] = f2bf(v.z); o[3] = f2bf(v.w);
    *reinterpret_cast<u16x4*>(dst + off) = o;
}

// ---------------------------------------------------------------- rope table
// tab[s*32+f] = (cos, sin) of pos[s] * theta^(-f/32)
__global__ __launch_bounds__(256) void rope_table_k(
    const int* __restrict__ pos, float2* __restrict__ tab)
{
    int i = blockIdx.x * 256 + threadIdx.x;   // 65536
    int s = i >> 5, f = i & 31;
    float inv = powf(10000.0f, -(float)f / 32.0f);
    float ang = (float)pos[s] * inv;
    tab[i] = make_float2(cosf(ang), sinf(ang));
}

// ---------------------------------------------------------------- GEMM
// C[m][n] = sum_k A[m][k] * W[n][k]   (A: MxK bf16 row-major, W: NxK bf16)
// MODE 0: scatter bf16 into [B,H,S,dh] (QKV, blockIdx.z picks W & dst)
// MODE 1: fp32 row-major out (O-proj)
template<int MODE>
__global__ __launch_bounds__(256) void gemm128(
    const ushort_t* __restrict__ A,
    const ushort_t* __restrict__ W0, const ushort_t* __restrict__ W1,
    const ushort_t* __restrict__ W2,
    ushort_t* __restrict__ D0, ushort_t* __restrict__ D1,
    ushort_t* __restrict__ D2,
    float* __restrict__ Fout)
{
    __shared__ __attribute__((aligned(16))) ushort_t As[128][40];
    __shared__ __attribute__((aligned(16))) ushort_t Bs[128][40];
    const ushort_t* W = (MODE == 1 || blockIdx.z == 0) ? W0
                        : (blockIdx.z == 1 ? W1 : W2);
    ushort_t* Dst = (blockIdx.z == 0) ? D0 : (blockIdx.z == 1) ? D1 : D2;
    int m0 = blockIdx.x * 128, n0 = blockIdx.y * 128;
    int tid = threadIdx.x, lane = tid & 63, wv = tid >> 6;
    int wm = wv >> 1, wn = wv & 1;
    int l15 = lane & 15, g = lane >> 4;

    f32x4 acc[4][4];
    for (int i = 0; i < 4; i++)
        for (int j = 0; j < 4; j++)
            acc[i][j] = (f32x4){0.f, 0.f, 0.f, 0.f};

    int ar0 = tid >> 2, ac0 = (tid & 3) * 8;
    for (int kk = 0; kk < DM; kk += 32) {
        *reinterpret_cast<short8*>(&As[ar0][ac0]) =
            *reinterpret_cast<const short8*>(&A[(size_t)(m0 + ar0) * DM + kk + ac0]);
        *reinterpret_cast<short8*>(&As[ar0 + 64][ac0]) =
            *reinterpret_cast<const short8*>(&A[(size_t)(m0 + ar0 + 64) * DM + kk + ac0]);
        *reinterpret_cast<short8*>(&Bs[ar0][ac0]) =
            *reinterpret_cast<const short8*>(&W[(size_t)(n0 + ar0) * DM + kk + ac0]);
        *reinterpret_cast<short8*>(&Bs[ar0 + 64][ac0]) =
            *reinterpret_cast<const short8*>(&W[(size_t)(n0 + ar0 + 64) * DM + kk + ac0]);
        __syncthreads();
        short8 af[4], bf[4];
        for (int i = 0; i < 4; i++)
            af[i] = *reinterpret_cast<const short8*>(&As[wm * 64 + i * 16 + l15][g * 8]);
        for (int j = 0; j < 4; j++)
            bf[j] = *reinterpret_cast<const short8*>(&Bs[wn * 64 + j * 16 + l15][g * 8]);
        for (int i = 0; i < 4; i++)
            for (int j = 0; j < 4; j++)
                acc[i][j] = __builtin_amdgcn_mfma_f32_16x16x32_bf16(
                    af[i], bf[j], acc[i][j], 0, 0, 0);
        __syncthreads();
    }

    for (int i = 0; i < 4; i++) {
        for (int j = 0; j < 4; j++) {
            int mbase = m0 + wm * 64 + i * 16 + g * 4;
            int n = n0 + wn * 64 + j * 16 + l15;
            if (MODE == 0) {
                int h = n >> 6, d = n & 63;
                for (int r = 0; r < 4; r++) {
                    int m = mbase + r;
                    int b = m >> 11, s = m & 2047;
                    Dst[(((size_t)(b * NH + h)) * S_LEN + s) * DH + d] =
                        f2bf(acc[i][j][r]);
                }
            } else {
                for (int r = 0; r < 4; r++)
                    Fout[(size_t)(mbase + r) * DM + n] = acc[i][j][r];
            }
        }
    }
}

// ---------------------------------------------------------------- rope apply
// in-place on Q,K bf16 [BH][S][64]; pairs (2f, 2f+1)
__global__ __launch_bounds__(256) void rope_apply_k(
    ushort_t* __restrict__ Qb, ushort_t* __restrict__ Kb,
    const float2* __restrict__ tab)
{
    int i = blockIdx.x * 256 + threadIdx.x;   // BH*S*32 = 2,097,152
    int sf = i & (S_LEN * 32 - 1);
    float2 cs = tab[sf];
    size_t off = ((size_t)(i >> 5)) * 64 + (size_t)(i & 31) * 2;

    uint_t uq = *reinterpret_cast<const uint_t*>(Qb + off);
    float e = bf2f((ushort_t)(uq & 0xffff)), o = bf2f((ushort_t)(uq >> 16));
    float re = e * cs.x - o * cs.y, ro = e * cs.y + o * cs.x;
    *reinterpret_cast<uint_t*>(Qb + off) =
        (uint_t)f2bf(re) | ((uint_t)f2bf(ro) << 16);

    uint_t uk = *reinterpret_cast<const uint_t*>(Kb + off);
    e = bf2f((ushort_t)(uk & 0xffff)); o = bf2f((ushort_t)(uk >> 16));
    re = e * cs.x - o * cs.y; ro = e * cs.y + o * cs.x;
    *reinterpret_cast<uint_t*>(Kb + off) =
        (uint_t)f2bf(re) | ((uint_t)f2bf(ro) << 16);
}

// ---------------------------------------------------------------- V transpose
// [BH][S][64] -> [BH][64][S]
__global__ __launch_bounds__(256) void transpose_v_k(
    const ushort_t* __restrict__ V, ushort_t* __restrict__ Vt)
{
    __shared__ float tile[64][65];
    int bh = blockIdx.y, s0 = blockIdx.x * 64;
    const ushort_t* src = V + ((size_t)bh * S_LEN + s0) * DH;
    int tid = threadIdx.x;
    for (int it = 0; it < 2; ++it) {
        int slot = tid + it * 256;
        int r = slot >> 3, cv = (slot & 7) * 8;
        short8 v8 = *reinterpret_cast<const short8*>(&src[r * DH + cv]);
        for (int j = 0; j < 8; j++) tile[r][cv + j] = bf2f((ushort_t)v8[j]);
    }
    __syncthreads();
    ushort_t* dst = Vt + (size_t)bh * DH * S_LEN + s0;
    for (int it = 0; it < 2; ++it) {
        int slot = tid + it * 256;
        int d = slot >> 3, sv = (slot & 7) * 8;
        short8 o;
        for (int j = 0; j < 8; j++) o[j] = (short)f2bf(tile[sv + j][d]);
        *reinterpret_cast<short8*>(&dst[(size_t)d * S_LEN + sv]) = o;
    }
}

// ---------------------------------------------------------------- attention
// causal flash attention; 1 wave = 16 q rows; 32-key blocks
// Q,K: bf16 [BH][S][64] (rope'd); Vt: bf16 [BH][64][S]
// out: bf16 [B][S][H*64]
__global__ __launch_bounds__(256) void attn_k(
    const ushort_t* __restrict__ Q, const ushort_t* __restrict__ K,
    const ushort_t* __restrict__ Vt, ushort_t* __restrict__ O)
{
    __shared__ __attribute__((aligned(16))) ushort_t Pl[4][16][40];
    int wv = threadIdx.x >> 6, lane = threadIdx.x & 63;
    int l15 = lane & 15, g = lane >> 4;
    int bh = blockIdx.y;
    int qbase = blockIdx.x * 64 + wv * 16;
    const ushort_t* Qp = Q + (size_t)bh * S_LEN * DH;
    const ushort_t* Kp = K + (size_t)bh * S_LEN * DH;
    const ushort_t* Vp = Vt + (size_t)bh * DH * S_LEN;

    short8 qf0 = *reinterpret_cast<const short8*>(&Qp[(qbase + l15) * DH + g * 8]);
    short8 qf1 = *reinterpret_cast<const short8*>(&Qp[(qbase + l15) * DH + 32 + g * 8]);

    f32x4 oacc[4];
    for (int dc = 0; dc < 4; dc++) oacc[dc] = (f32x4){0.f, 0.f, 0.f, 0.f};
    float mrow[4] = {-INFINITY, -INFINITY, -INFINITY, -INFINITY};
    float lrow[4] = {0.f, 0.f, 0.f, 0.f};

    int nkb = (qbase + 47) >> 5;
    for (int kb = 0; kb < nkb; ++kb) {
        int k0 = kb * 32;
        f32x4 sc0 = {0.f, 0.f, 0.f, 0.f}, sc1 = {0.f, 0.f, 0.f, 0.f};
        {
            const ushort_t* kp = &Kp[(k0 + l15) * DH + g * 8];
            short8 kf0 = *reinterpret_cast<const short8*>(kp);
            short8 kf1 = *reinterpret_cast<const short8*>(kp + 32);
            sc0 = __builtin_amdgcn_mfma_f32_16x16x32_bf16(qf0, kf0, sc0, 0, 0, 0);
            sc0 = __builtin_amdgcn_mfma_f32_16x16x32_bf16(qf1, kf1, sc0, 0, 0, 0);
        }
        {
            const ushort_t* kp = &Kp[(k0 + 16 + l15) * DH + g * 8];
            short8 kf0 = *reinterpret_cast<const short8*>(kp);
            short8 kf1 = *reinterpret_cast<const short8*>(kp + 32);
            sc1 = __builtin_amdgcn_mfma_f32_16x16x32_bf16(qf0, kf0, sc1, 0, 0, 0);
            sc1 = __builtin_amdgcn_mfma_f32_16x16x32_bf16(qf1, kf1, sc1, 0, 0, 0);
        }
        // scale + causal mask, in D layout: row q = qbase+g*4+r, col key
        float s4[2][4], mt[4];
        for (int r = 0; r < 4; r++) {
            int qrow = qbase + g * 4 + r;
            int key0 = k0 + l15, key1 = k0 + 16 + l15;
            float v0 = sc0[r] * 0.125f, v1 = sc1[r] * 0.125f;
            if (key0 > qrow) v0 = -1e30f;
            if (key1 > qrow) v1 = -1e30f;
            s4[0][r] = v0; s4[1][r] = v1;
            mt[r] = fmaxf(v0, v1);
        }
        for (int off = 1; off < 16; off <<= 1)
            for (int r = 0; r < 4; r++)
                mt[r] = fmaxf(mt[r], __shfl_xor(mt[r], off));
        float al[4];
        for (int r = 0; r < 4; r++) {
            float mn = fmaxf(mrow[r], mt[r]);
            al[r] = __expf(mrow[r] - mn);
            mrow[r] = mn;
        }
        float ps[4] = {0.f, 0.f, 0.f, 0.f};
        for (int t = 0; t < 2; t++)
            for (int r = 0; r < 4; r++) {
                float p = __expf(s4[t][r] - mrow[r]);
                ps[r] += p;
                Pl[wv][g * 4 + r][t * 16 + l15] = f2bf(p);
            }
        for (int off = 1; off < 16; off <<= 1)
            for (int r = 0; r < 4; r++)
                ps[r] += __shfl_xor(ps[r], off);
        for (int r = 0; r < 4; r++) lrow[r] = lrow[r] * al[r] + ps[r];
        for (int dc = 0; dc < 4; dc++)
            for (int r = 0; r < 4; r++) oacc[dc][r] *= al[r];
        // PV: A = P (16q x 32k) from LDS, B = Vt (32k x 16d) from global
        short8 pf = *reinterpret_cast<const short8*>(&Pl[wv][l15][g * 8]);
        for (int dc = 0; dc < 4; dc++) {
            short8 vf = *reinterpret_cast<const short8*>(
                &Vp[(size_t)(dc * 16 + l15) * S_LEN + k0 + g * 8]);
            oacc[dc] = __builtin_amdgcn_mfma_f32_16x16x32_bf16(pf, vf, oacc[dc], 0, 0, 0);
        }
    }

    int b = bh >> 4, h = bh & 15;
    for (int r = 0; r < 4; r++) {
        float inv = 1.0f / lrow[r];
        int q = qbase + g * 4 + r;
        size_t base = ((size_t)b * S_LEN + q) * DM + h * DH + l15;
        for (int dc = 0; dc < 4; dc++)
            O[base + dc * 16] = f2bf(oacc[dc][r] * inv);
    }
}

// ---------------------------------------------------------------- launch
extern "C" void kernel_launch(void* const* d_in, const int* in_sizes, int n_in,
                              void* d_out, int out_size, void* d_ws, size_t ws_size,
                              hipStream_t stream)
{
    const float* X  = (const float*)d_in[0];
    const int* pos  = (const int*)d_in[1];
    const float* qw = (const float*)d_in[2];
    const float* kw = (const float*)d_in[3];
    const float* vw = (const float*)d_in[4];
    const float* ow = (const float*)d_in[5];
    float* out = (float*)d_out;

    char* ws = (char*)d_ws;
    ushort_t* Xb   = (ushort_t*)(ws);               //  8 MB  X bf16
    ushort_t* Wqb  = (ushort_t*)(ws + 8388608);     //  2 MB
    ushort_t* Wkb  = (ushort_t*)(ws + 10485760);    //  2 MB
    ushort_t* Wvb  = (ushort_t*)(ws + 12582912);    //  2 MB
    ushort_t* Wob  = (ushort_t*)(ws + 14680064);    //  2 MB
    ushort_t* Qbh  = (ushort_t*)(ws + 16777216);    //  8 MB [BH][S][64]
    ushort_t* Kbh  = (ushort_t*)(ws + 25165824);    //  8 MB
    ushort_t* Vbh  = (ushort_t*)(ws + 33554432);    //  8 MB
    ushort_t* Vtb  = (ushort_t*)(ws + 41943040);    //  8 MB [BH][64][S]
    ushort_t* AttO = (ushort_t*)(ws + 50331648);    //  8 MB [B][S][1024]
    float2*   tab  = (float2*)(ws + 58720256);      //  0.5 MB

    convert_all<<<8192, 256, 0, stream>>>(X, qw, kw, vw, ow,
                                          Xb, Wqb, Wkb, Wvb, Wob);
    rope_table_k<<<256, 256, 0, stream>>>(pos, tab);
    gemm128<0><<<dim3(32, 8, 3), 256, 0, stream>>>(
        Xb, Wqb, Wkb, Wvb, Qbh, Kbh, Vbh, nullptr);
    rope_apply_k<<<8192, 256, 0, stream>>>(Qbh, Kbh, tab);
    transpose_v_k<<<dim3(32, 32), 256, 0, stream>>>(Vbh, Vtb);
    attn_k<<<dim3(32, 32), 256, 0, stream>>>(Qbh, Kbh, Vtb, AttO);
    gemm128<1><<<dim3(32, 8, 1), 256, 0, stream>>>(
        AttO, Wob, nullptr, nullptr, nullptr, nullptr, nullptr, out);
}

// Round 2
// 218.348 us; speedup vs baseline: 1.4295x; 1.4295x over previous
//
#include <hip/hip_runtime.h>
#include <hip/hip_bf16.h>

typedef unsigned short ushort_t;
typedef unsigned int uint_t;
typedef __attribute__((ext_vector_type(4))) float f32x4;
typedef __attribute__((ext_vector_type(8))) short short8;
typedef __attribute__((ext_vector_type(4))) unsigned short u16x4;
typedef __attribute__((ext_vector_type(4))) uint_t u32x4;

#define S_LEN 2048
#define DM 1024
#define NH 16
#define DH 64
#define NB 2
#define BH (NB*NH)          // 32
#define MROWS (NB*S_LEN)    // 4096

__device__ __forceinline__ float bf2f(ushort_t u) {
    return __uint_as_float(((uint_t)u) << 16);
}
__device__ __forceinline__ ushort_t f2bf(float f) {
    __hip_bfloat16 h = __float2bfloat16(f);
    return *reinterpret_cast<ushort_t*>(&h);
}

// ---------------------------------------------------------------- convert
__global__ __launch_bounds__(256) void convert_all(
    const float* __restrict__ X,  const float* __restrict__ Wq,
    const float* __restrict__ Wk, const float* __restrict__ Wv,
    const float* __restrict__ Wo,
    ushort_t* __restrict__ Xb,  ushort_t* __restrict__ Wqb,
    ushort_t* __restrict__ Wkb, ushort_t* __restrict__ Wvb,
    ushort_t* __restrict__ Wob)
{
    size_t i = (size_t)blockIdx.x * 256 + threadIdx.x;
    size_t e = i * 4;
    const float* src; ushort_t* dst; size_t off;
    if (e < (size_t)MROWS * DM) { src = X; dst = Xb; off = e; }
    else {
        size_t r = e - (size_t)MROWS * DM;
        int w = (int)(r >> 20); off = r & 1048575;
        src = (w == 0) ? Wq : (w == 1) ? Wk : (w == 2) ? Wv : Wo;
        dst = (w == 0) ? Wqb : (w == 1) ? Wkb : (w == 2) ? Wvb : Wob;
    }
    float4 v = *reinterpret_cast<const float4*>(src + off);
    u16x4 o;
    o[0] = f2bf(v.x); o[1] = f2bf(v.y); o[2] = f2bf(v.z); o[3] = f2bf(v.w);
    *reinterpret_cast<u16x4*>(dst + off) = o;
}

// ---------------------------------------------------------------- rope table
__global__ __launch_bounds__(256) void rope_table_k(
    const int* __restrict__ pos, float2* __restrict__ tab)
{
    int i = blockIdx.x * 256 + threadIdx.x;   // 65536
    int s = i >> 5, f = i & 31;
    float inv = powf(10000.0f, -(float)f / 32.0f);
    float ang = (float)pos[s] * inv;
    tab[i] = make_float2(cosf(ang), sinf(ang));
}

// ---------------------------------------------------------------- GEMM
template<int MODE>
__global__ __launch_bounds__(256) void gemm128(
    const ushort_t* __restrict__ A,
    const ushort_t* __restrict__ W0, const ushort_t* __restrict__ W1,
    const ushort_t* __restrict__ W2,
    ushort_t* __restrict__ D0, ushort_t* __restrict__ D1,
    ushort_t* __restrict__ D2,
    float* __restrict__ Fout)
{
    __shared__ __attribute__((aligned(16))) ushort_t As[128][40];
    __shared__ __attribute__((aligned(16))) ushort_t Bs[128][40];
    const ushort_t* W = (MODE == 1 || blockIdx.z == 0) ? W0
                        : (blockIdx.z == 1 ? W1 : W2);
    ushort_t* Dst = (blockIdx.z == 0) ? D0 : (blockIdx.z == 1) ? D1 : D2;
    int m0 = blockIdx.x * 128, n0 = blockIdx.y * 128;
    int tid = threadIdx.x, lane = tid & 63, wv = tid >> 6;
    int wm = wv >> 1, wn = wv & 1;
    int l15 = lane & 15, g = lane >> 4;

    f32x4 acc[4][4];
    for (int i = 0; i < 4; i++)
        for (int j = 0; j < 4; j++)
            acc[i][j] = (f32x4){0.f, 0.f, 0.f, 0.f};

    int ar0 = tid >> 2, ac0 = (tid & 3) * 8;
    for (int kk = 0; kk < DM; kk += 32) {
        *reinterpret_cast<short8*>(&As[ar0][ac0]) =
            *reinterpret_cast<const short8*>(&A[(size_t)(m0 + ar0) * DM + kk + ac0]);
        *reinterpret_cast<short8*>(&As[ar0 + 64][ac0]) =
            *reinterpret_cast<const short8*>(&A[(size_t)(m0 + ar0 + 64) * DM + kk + ac0]);
        *reinterpret_cast<short8*>(&Bs[ar0][ac0]) =
            *reinterpret_cast<const short8*>(&W[(size_t)(n0 + ar0) * DM + kk + ac0]);
        *reinterpret_cast<short8*>(&Bs[ar0 + 64][ac0]) =
            *reinterpret_cast<const short8*>(&W[(size_t)(n0 + ar0 + 64) * DM + kk + ac0]);
        __syncthreads();
        short8 af[4], bf[4];
        for (int i = 0; i < 4; i++)
            af[i] = *reinterpret_cast<const short8*>(&As[wm * 64 + i * 16 + l15][g * 8]);
        for (int j = 0; j < 4; j++)
            bf[j] = *reinterpret_cast<const short8*>(&Bs[wn * 64 + j * 16 + l15][g * 8]);
        for (int i = 0; i < 4; i++)
            for (int j = 0; j < 4; j++)
                acc[i][j] = __builtin_amdgcn_mfma_f32_16x16x32_bf16(
                    af[i], bf[j], acc[i][j], 0, 0, 0);
        __syncthreads();
    }

    for (int i = 0; i < 4; i++) {
        for (int j = 0; j < 4; j++) {
            int mbase = m0 + wm * 64 + i * 16 + g * 4;
            int n = n0 + wn * 64 + j * 16 + l15;
            if (MODE == 0) {
                int h = n >> 6, d = n & 63;
                for (int r = 0; r < 4; r++) {
                    int m = mbase + r;
                    int b = m >> 11, s = m & 2047;
                    Dst[(((size_t)(b * NH + h)) * S_LEN + s) * DH + d] =
                        f2bf(acc[i][j][r]);
                }
            } else {
                for (int r = 0; r < 4; r++)
                    Fout[(size_t)(mbase + r) * DM + n] = acc[i][j][r];
            }
        }
    }
}

// ---------------------------------------------------------------- rope apply
__global__ __launch_bounds__(256) void rope_apply_k(
    ushort_t* __restrict__ Qb, ushort_t* __restrict__ Kb,
    const float2* __restrict__ tab)
{
    int i = blockIdx.x * 256 + threadIdx.x;
    int sf = i & (S_LEN * 32 - 1);
    float2 cs = tab[sf];
    size_t off = ((size_t)(i >> 5)) * 64 + (size_t)(i & 31) * 2;

    uint_t uq = *reinterpret_cast<const uint_t*>(Qb + off);
    float e = bf2f((ushort_t)(uq & 0xffff)), o = bf2f((ushort_t)(uq >> 16));
    float re = e * cs.x - o * cs.y, ro = e * cs.y + o * cs.x;
    *reinterpret_cast<uint_t*>(Qb + off) =
        (uint_t)f2bf(re) | ((uint_t)f2bf(ro) << 16);

    uint_t uk = *reinterpret_cast<const uint_t*>(Kb + off);
    e = bf2f((ushort_t)(uk & 0xffff)); o = bf2f((ushort_t)(uk >> 16));
    re = e * cs.x - o * cs.y; ro = e * cs.y + o * cs.x;
    *reinterpret_cast<uint_t*>(Kb + off) =
        (uint_t)f2bf(re) | ((uint_t)f2bf(ro) << 16);
}

// ---------------------------------------------------------------- V transpose
// [BH][S][64] -> [BH][64][S]
__global__ __launch_bounds__(256) void transpose_v_k(
    const ushort_t* __restrict__ V, ushort_t* __restrict__ Vt)
{
    __shared__ float tile[64][65];
    int bh = blockIdx.y, s0 = blockIdx.x * 64;
    const ushort_t* src = V + ((size_t)bh * S_LEN + s0) * DH;
    int tid = threadIdx.x;
    for (int it = 0; it < 2; ++it) {
        int slot = tid + it * 256;
        int r = slot >> 3, cv = (slot & 7) * 8;
        short8 v8 = *reinterpret_cast<const short8*>(&src[r * DH + cv]);
        for (int j = 0; j < 8; j++) tile[r][cv + j] = bf2f((ushort_t)v8[j]);
    }
    __syncthreads();
    ushort_t* dst = Vt + (size_t)bh * DH * S_LEN + s0;
    for (int it = 0; it < 2; ++it) {
        int slot = tid + it * 256;
        int d = slot >> 3, sv = (slot & 7) * 8;
        short8 o;
        for (int j = 0; j < 8; j++) o[j] = (short)f2bf(tile[sv + j][d]);
        *reinterpret_cast<short8*>(&dst[(size_t)d * S_LEN + sv]) = o;
    }
}

// ---------------------------------------------------------------- attention
// Swapped-operand flash attention. 1 wave = 16 q (q = qbase + (lane&15)),
// KVBLK = 64 keys. S^T = mfma(K,Q): col=q=l15, row=key=g*4+r.
// m/l are per-lane scalars; reduce = tree + 2 shfl_xor.
// PV: O^T = mfma(V^T, P); P redistributed in-register via 16 bpermute/64keys.
template<bool MASK>
__device__ __forceinline__ void attn_step64(
    int k0, int qbase, int l15, int g,
    const ushort_t* __restrict__ Kp, const ushort_t* __restrict__ Vp,
    short8 qf0, short8 qf1,
    f32x4 (&oacc)[4], float& m_run, float& l_run)
{
    // K fragments: 8 x 16B loads
    short8 kf0[4], kf1[4];
    #pragma unroll
    for (int t = 0; t < 4; t++) {
        const ushort_t* kp = &Kp[(size_t)(k0 + t * 16 + l15) * DH + g * 8];
        kf0[t] = *reinterpret_cast<const short8*>(kp);
        kf1[t] = *reinterpret_cast<const short8*>(kp + 32);
    }
    // S^T tiles: st[t] holds keys k0+t*16+g*4+r for query qbase+l15
    f32x4 st[4];
    #pragma unroll
    for (int t = 0; t < 4; t++) {
        f32x4 z = {0.f, 0.f, 0.f, 0.f};
        z = __builtin_amdgcn_mfma_f32_16x16x32_bf16(kf0[t], qf0, z, 0, 0, 0);
        z = __builtin_amdgcn_mfma_f32_16x16x32_bf16(kf1[t], qf1, z, 0, 0, 0);
        st[t] = z;
    }
    // V^T fragments issued early: overlap softmax with their latency
    short8 vf[2][4];
    #pragma unroll
    for (int ts = 0; ts < 2; ts++)
        #pragma unroll
        for (int dc = 0; dc < 4; dc++)
            vf[ts][dc] = *reinterpret_cast<const short8*>(
                &Vp[(size_t)(dc * 16 + l15) * S_LEN + k0 + ts * 32 + g * 8]);

    int q = qbase + l15;
    #pragma unroll
    for (int t = 0; t < 4; t++)
        #pragma unroll
        for (int r = 0; r < 4; r++) {
            float v = st[t][r] * 0.125f;
            if (MASK && (k0 + t * 16 + g * 4 + r) > q) v = -1e30f;
            st[t][r] = v;
        }
    // max over 16 (tree) + 2 shfl
    float ma = fmaxf(fmaxf(st[0][0], st[0][1]), fmaxf(st[0][2], st[0][3]));
    float mb = fmaxf(fmaxf(st[1][0], st[1][1]), fmaxf(st[1][2], st[1][3]));
    float mc = fmaxf(fmaxf(st[2][0], st[2][1]), fmaxf(st[2][2], st[2][3]));
    float md = fmaxf(fmaxf(st[3][0], st[3][1]), fmaxf(st[3][2], st[3][3]));
    float m16 = fmaxf(fmaxf(ma, mb), fmaxf(mc, md));
    m16 = fmaxf(m16, __shfl_xor(m16, 16));
    m16 = fmaxf(m16, __shfl_xor(m16, 32));
    float m_new = fmaxf(m_run, m16);
    float alpha = __expf(m_run - m_new);
    m_run = m_new;

    float ps = 0.f;
    uint_t pk[4][2];
    #pragma unroll
    for (int t = 0; t < 4; t++) {
        float p0 = __expf(st[t][0] - m_new);
        float p1 = __expf(st[t][1] - m_new);
        float p2 = __expf(st[t][2] - m_new);
        float p3 = __expf(st[t][3] - m_new);
        ps += (p0 + p1) + (p2 + p3);
        pk[t][0] = (uint_t)f2bf(p0) | ((uint_t)f2bf(p1) << 16);
        pk[t][1] = (uint_t)f2bf(p2) | ((uint_t)f2bf(p3) << 16);
    }
    ps += __shfl_xor(ps, 16);
    ps += __shfl_xor(ps, 32);
    l_run = l_run * alpha + ps;
    #pragma unroll
    for (int dc = 0; dc < 4; dc++) oacc[dc] *= alpha;

    // Redistribute P to PV B-operand layout: receiver lane (g,l15) needs
    // keys g*8..g*8+7 (within ts*32 subtile) for its query l15.
    int lane_a = (g & 1) * 32 + l15;
    int lane_b = lane_a + 16;
    bool lo = (g < 2);
    #pragma unroll
    for (int ts = 0; ts < 2; ts++) {
        uint_t a0 = (uint_t)__shfl((int)pk[ts * 2][0], lane_a);
        uint_t a1 = (uint_t)__shfl((int)pk[ts * 2][1], lane_a);
        uint_t a2 = (uint_t)__shfl((int)pk[ts * 2][0], lane_b);
        uint_t a3 = (uint_t)__shfl((int)pk[ts * 2][1], lane_b);
        uint_t b0 = (uint_t)__shfl((int)pk[ts * 2 + 1][0], lane_a);
        uint_t b1 = (uint_t)__shfl((int)pk[ts * 2 + 1][1], lane_a);
        uint_t b2 = (uint_t)__shfl((int)pk[ts * 2 + 1][0], lane_b);
        uint_t b3 = (uint_t)__shfl((int)pk[ts * 2 + 1][1], lane_b);
        u32x4 w = { lo ? a0 : b0, lo ? a1 : b1, lo ? a2 : b2, lo ? a3 : b3 };
        short8 pf = __builtin_bit_cast(short8, w);
        #pragma unroll
        for (int dc = 0; dc < 4; dc++)
            oacc[dc] = __builtin_amdgcn_mfma_f32_16x16x32_bf16(
                vf[ts][dc], pf, oacc[dc], 0, 0, 0);
    }
}

__global__ __launch_bounds__(256) void attn_k2(
    const ushort_t* __restrict__ Q, const ushort_t* __restrict__ K,
    const ushort_t* __restrict__ Vt, ushort_t* __restrict__ O)
{
    int wv = threadIdx.x >> 6, lane = threadIdx.x & 63;
    int l15 = lane & 15, g = lane >> 4;
    int bid = blockIdx.x;
    int qt = 31 - (bid >> 5);     // longest q-tiles dispatched first
    int bh = bid & 31;
    int qbase = qt * 64 + wv * 16;
    const ushort_t* Qp = Q + (size_t)bh * S_LEN * DH;
    const ushort_t* Kp = K + (size_t)bh * S_LEN * DH;
    const ushort_t* Vp = Vt + (size_t)bh * DH * S_LEN;

    short8 qf0 = *reinterpret_cast<const short8*>(&Qp[(qbase + l15) * DH + g * 8]);
    short8 qf1 = *reinterpret_cast<const short8*>(&Qp[(qbase + l15) * DH + 32 + g * 8]);

    f32x4 oacc[4];
    #pragma unroll
    for (int dc = 0; dc < 4; dc++) oacc[dc] = (f32x4){0.f, 0.f, 0.f, 0.f};
    float m_run = -INFINITY, l_run = 0.f;

    int full64 = qbase >> 6;
    for (int kb = 0; kb < full64; ++kb)
        attn_step64<false>(kb * 64, qbase, l15, g, Kp, Vp, qf0, qf1,
                           oacc, m_run, l_run);
    attn_step64<true>(full64 * 64, qbase, l15, g, Kp, Vp, qf0, qf1,
                      oacc, m_run, l_run);

    float inv = 1.0f / l_run;
    int b = bh >> 4, h = bh & 15;
    int q = qbase + l15;
    size_t base = ((size_t)b * S_LEN + q) * DM + h * DH;
    #pragma unroll
    for (int dc = 0; dc < 4; dc++) {
        u16x4 o;
        #pragma unroll
        for (int r = 0; r < 4; r++) o[r] = f2bf(oacc[dc][r] * inv);
        *reinterpret_cast<u16x4*>(&O[base + dc * 16 + g * 4]) = o;
    }
}

// ---------------------------------------------------------------- launch
extern "C" void kernel_launch(void* const* d_in, const int* in_sizes, int n_in,
                              void* d_out, int out_size, void* d_ws, size_t ws_size,
                              hipStream_t stream)
{
    const float* X  = (const float*)d_in[0];
    const int* pos  = (const int*)d_in[1];
    const float* qw = (const float*)d_in[2];
    const float* kw = (const float*)d_in[3];
    const float* vw = (const float*)d_in[4];
    const float* ow = (const float*)d_in[5];
    float* out = (float*)d_out;

    char* ws = (char*)d_ws;
    ushort_t* Xb   = (ushort_t*)(ws);               //  8 MB  X bf16
    ushort_t* Wqb  = (ushort_t*)(ws + 8388608);     //  2 MB
    ushort_t* Wkb  = (ushort_t*)(ws + 10485760);    //  2 MB
    ushort_t* Wvb  = (ushort_t*)(ws + 12582912);    //  2 MB
    ushort_t* Wob  = (ushort_t*)(ws + 14680064);    //  2 MB
    ushort_t* Qbh  = (ushort_t*)(ws + 16777216);    //  8 MB [BH][S][64]
    ushort_t* Kbh  = (ushort_t*)(ws + 25165824);    //  8 MB
    ushort_t* Vbh  = (ushort_t*)(ws + 33554432);    //  8 MB
    ushort_t* Vtb  = (ushort_t*)(ws + 41943040);    //  8 MB [BH][64][S]
    ushort_t* AttO = (ushort_t*)(ws + 50331648);    //  8 MB [B][S][1024]
    float2*   tab  = (float2*)(ws + 58720256);      //  0.5 MB

    convert_all<<<8192, 256, 0, stream>>>(X, qw, kw, vw, ow,
                                          Xb, Wqb, Wkb, Wvb, Wob);
    rope_table_k<<<256, 256, 0, stream>>>(pos, tab);
    gemm128<0><<<dim3(32, 8, 3), 256, 0, stream>>>(
        Xb, Wqb, Wkb, Wvb, Qbh, Kbh, Vbh, nullptr);
    rope_apply_k<<<8192, 256, 0, stream>>>(Qbh, Kbh, tab);
    transpose_v_k<<<dim3(32, 32), 256, 0, stream>>>(Vbh, Vtb);
    attn_k2<<<1024, 256, 0, stream>>>(Qbh, Kbh, Vtb, AttO);
    gemm128<1><<<dim3(32, 8, 1), 256, 0, stream>>>(
        AttO, Wob, nullptr, nullptr, nullptr, nullptr, nullptr, out);
}